// Round 3
// baseline (149.817 us; speedup 1.0000x reference)
//
#include <hip/hip_runtime.h>
#include <math.h>

#define BB 64
#define SS 8192
#define IN_DIM 512
#define OUT_DIM 128
#define DVV 128
#define CHUNK 256
#define NCHUNK (SS / CHUNK)   // 32

// Kernel 1: qt[b] = (Wk @ (q[b] @ Wq)) / sqrt(OUT_DIM)   (512 threads, 4-way split-K)
__global__ __launch_bounds__(512) void qt_kernel(const float* __restrict__ q,
                          const float* __restrict__ Wq,
                          const float* __restrict__ Wk,
                          float* __restrict__ qt) {
    int b = blockIdx.x;
    int t = threadIdx.x;
    int e = t & 127;          // output index
    int h = t >> 7;           // split 0..3
    __shared__ float part[4][OUT_DIM];
    __shared__ float qs[OUT_DIM];

    const float* qb = q + (size_t)b * IN_DIM;
    float acc = 0.f;
    for (int i = h * (IN_DIM / 4); i < (h + 1) * (IN_DIM / 4); ++i)
        acc = fmaf(qb[i], Wq[(size_t)i * OUT_DIM + e], acc);
    part[h][e] = acc;
    __syncthreads();
    if (h == 0) qs[e] = part[0][e] + part[1][e] + part[2][e] + part[3][e];
    __syncthreads();

    float a2 = 0.f;
    const float* wkrow = Wk + (size_t)e * OUT_DIM;
    for (int i = h * (OUT_DIM / 4); i < (h + 1) * (OUT_DIM / 4); ++i)
        a2 = fmaf(wkrow[i], qs[i], a2);
    part[h][e] = a2;
    __syncthreads();
    if (h == 0)
        qt[(size_t)b * OUT_DIM + e] =
            (part[0][e] + part[1][e] + part[2][e] + part[3][e]) * 0.08838834764831845f;
}

// Kernel A: pure k-stream. Per (b, chunk of 256 rows): raw scores -> ws,
// per-chunk (m, l=sum exp(s-m)). All loop iterations independent; barriers
// only after every load has been issued.
__global__ __launch_bounds__(256) void score_kernel(
    const float* __restrict__ k, const float* __restrict__ qt,
    float* __restrict__ scores, float* __restrict__ ml) {
    int blk = blockIdx.x;
    int b = blk >> 5;        // / NCHUNK
    int c = blk & 31;
    int s0 = c * CHUNK;
    int t = threadIdx.x;
    int wave = t >> 6, lane = t & 63, half = lane >> 5, l32 = lane & 31;

    __shared__ float4 qts4[OUT_DIM / 4];
    __shared__ float sc[CHUNK];
    __shared__ float wred[4];

    if (t < OUT_DIM / 4)
        qts4[t] = ((const float4*)(qt + (size_t)b * OUT_DIM))[t];
    __syncthreads();
    float4 qv = qts4[l32];

    const float4* k4 = (const float4*)(k + (size_t)b * SS * OUT_DIM);
    int r = wave * 2 + half;   // 0..7
    #pragma unroll
    for (int j = 0; j < CHUNK / 8; ++j) {
        int i = r + 8 * j;
        float4 kv = k4[(size_t)(s0 + i) * (OUT_DIM / 4) + l32];
        float p = kv.x * qv.x + kv.y * qv.y + kv.z * qv.z + kv.w * qv.w;
        p += __shfl_xor(p, 1);
        p += __shfl_xor(p, 2);
        p += __shfl_xor(p, 4);
        p += __shfl_xor(p, 8);
        p += __shfl_xor(p, 16);
        if (l32 == 0) sc[i] = p;
    }
    __syncthreads();

    float s = sc[t];
    scores[(size_t)b * SS + s0 + t] = s;   // raw score, coalesced

    float m = s;
    for (int d = 1; d < 64; d <<= 1) m = fmaxf(m, __shfl_xor(m, d));
    if (lane == 0) wred[wave] = m;
    __syncthreads();
    m = fmaxf(fmaxf(wred[0], wred[1]), fmaxf(wred[2], wred[3]));
    __syncthreads();

    float l = __expf(s - m);
    for (int d = 1; d < 64; d <<= 1) l += __shfl_xor(l, d);
    if (lane == 0) wred[wave] = l;
    __syncthreads();
    if (t == 0) {
        ml[blk * 2 + 0] = m;
        ml[blk * 2 + 1] = wred[0] + wred[1] + wred[2] + wred[3];
    }
}

// Kernel B: pure v-stream. Per (b, chunk): reduce the 32 (m,l) pairs of this
// batch in-block (redundant, tiny), build globally-normalized weights, then
// stream v with independent FMA iterations; tree-reduce; write partial ctx.
__global__ __launch_bounds__(256) void ctx_kernel(
    const float* __restrict__ v, const float* __restrict__ scores,
    const float* __restrict__ ml, float* __restrict__ ctx) {
    int blk = blockIdx.x;
    int b = blk >> 5;
    int c = blk & 31;
    int s0 = c * CHUNK;
    int t = threadIdx.x;

    __shared__ float mlsh[NCHUNK * 2];
    __shared__ float wl[CHUNK];
    __shared__ float4 red[256];

    if (t < NCHUNK * 2) mlsh[t] = ml[b * NCHUNK * 2 + t];
    __syncthreads();
    float M = mlsh[0];
    #pragma unroll
    for (int i = 1; i < NCHUNK; ++i) M = fmaxf(M, mlsh[2 * i]);
    float L = 0.f;
    #pragma unroll
    for (int i = 0; i < NCHUNK; ++i) L += mlsh[2 * i + 1] * __expf(mlsh[2 * i] - M);
    float invL = 1.f / L;

    wl[t] = __expf(scores[(size_t)b * SS + s0 + t] - M) * invL;
    __syncthreads();

    int col = t & 31, rg = t >> 5;
    const float4* v4 = (const float4*)(v + (size_t)b * SS * DVV);
    float4 acc = make_float4(0.f, 0.f, 0.f, 0.f);
    #pragma unroll
    for (int j = 0; j < CHUNK / 8; ++j) {
        int i = rg + 8 * j;
        float4 vv = v4[(size_t)(s0 + i) * (DVV / 4) + col];
        float w = wl[i];
        acc.x = fmaf(w, vv.x, acc.x);
        acc.y = fmaf(w, vv.y, acc.y);
        acc.z = fmaf(w, vv.z, acc.z);
        acc.w = fmaf(w, vv.w, acc.w);
    }
    red[t] = acc;
    __syncthreads();
    for (int off = 128; off >= 32; off >>= 1) {
        if (t < off) {
            float4 o = red[t + off];
            red[t].x += o.x; red[t].y += o.y;
            red[t].z += o.z; red[t].w += o.w;
        }
        __syncthreads();
    }
    if (t < 32)
        ((float4*)(ctx + (size_t)blk * DVV))[t] = red[t];
}

// Kernel C: out[b] = sum over 32 chunk partials (already globally normalized)
__global__ void sum_kernel(const float* __restrict__ ctx, float* __restrict__ out) {
    int b = blockIdx.x;
    int t = threadIdx.x;  // 128
    float acc = 0.f;
    #pragma unroll
    for (int c = 0; c < NCHUNK; ++c)
        acc += ctx[((size_t)b * NCHUNK + c) * DVV + t];
    out[(size_t)b * DVV + t] = acc;
}

extern "C" void kernel_launch(void* const* d_in, const int* in_sizes, int n_in,
                              void* d_out, int out_size, void* d_ws, size_t ws_size,
                              hipStream_t stream) {
    const float* k  = (const float*)d_in[0];
    const float* q  = (const float*)d_in[1];
    const float* v  = (const float*)d_in[2];
    const float* Wk = (const float*)d_in[3];
    const float* Wq = (const float*)d_in[4];
    float* out = (float*)d_out;

    float* qt     = (float*)d_ws;                    // B*128
    float* ml     = qt + BB * OUT_DIM;               // B*NCHUNK*2
    float* ctx    = ml + BB * NCHUNK * 2;            // B*NCHUNK*128
    float* scores = ctx + BB * NCHUNK * DVV;         // B*S (2 MB)

    qt_kernel<<<BB, 512, 0, stream>>>(q, Wq, Wk, qt);
    score_kernel<<<BB * NCHUNK, 256, 0, stream>>>(k, qt, scores, ml);
    ctx_kernel<<<BB * NCHUNK, 256, 0, stream>>>(v, scores, ml, ctx);
    sum_kernel<<<BB, DVV, 0, stream>>>(ctx, out);
}